// Round 6
// baseline (354.515 us; speedup 1.0000x reference)
//
#include <hip/hip_runtime.h>
#include <hip/hip_bf16.h>

#define NN 100000      // nodes
#define EE 1600000     // edges
#define CIN 128        // in channels
#define HID 64         // hidden
#define NG 64          // graphs
#define NOUT 10        // out channels
#define BSZ 32         // targets per bucket (NN = 3125*32 exactly)
#define NB 3125        // number of buckets
#define CAP 768        // bucket capacity (mean 512, +11 sigma)

typedef short s16x8 __attribute__((ext_vector_type(8)));
typedef float f32x4 __attribute__((ext_vector_type(4)));

__device__ __forceinline__ unsigned short f2b(float f) {  // f32 -> bf16 RNE
  unsigned int b = __float_as_uint(f);
  return (unsigned short)((b + 0x7FFFu + ((b >> 16) & 1u)) >> 16);
}
__device__ __forceinline__ float b2f(unsigned short h) {  // bf16 -> f32 exact
  return __uint_as_float(((unsigned int)h) << 16);
}

// ---------------------------------------------------------------------------
// K0: W prep — Wt[n][k] = bf16(W[k][n]), n: 0-63 Wl cols, 64-127 Wr cols.
// ---------------------------------------------------------------------------
__global__ __launch_bounds__(256) void k_prep(const float* __restrict__ Wl,
                                              const float* __restrict__ Wr,
                                              unsigned short* __restrict__ Wt) {
  int flat = blockIdx.x * 2048 + threadIdx.x;
  for (int i = 0; i < 8; ++i, flat += 256) {
    int n = flat & 127, k = flat >> 7;
    float v = (n < 64) ? Wl[k * 64 + n] : Wr[k * 64 + (n - 64)];
    Wt[n * 128 + k] = f2b(v);
  }
}

// ---------------------------------------------------------------------------
// K1: [xl|xr] = bf16( x @ [Wl|Wr] ) via mfma_f32_16x16x32_bf16.
// Block: 128 nodes x 128 cols, 4 waves; wave w owns rows [w*32, w*32+32).
// LDS A[128][128] bf16 (x tile), B[128][128] bf16 (Wt), both XOR-swizzled
// (byte ^= (row&7)<<4 on 16B slots) for conflict-free ds_read_b128.
// Fragments (m89-verified): A: lane holds A[l&15][(l>>4)*8+j]; B: B-frag from
// col-major-staged Wt; D: row=(l>>4)*4+r, col=l&15.
// ---------------------------------------------------------------------------
__global__ __launch_bounds__(256) void k_gemm(
    const float* __restrict__ x, const unsigned short* __restrict__ Wt,
    unsigned short* __restrict__ xl, unsigned short* __restrict__ xr) {
  __shared__ unsigned short A[128 * 128];  // 32KB (reused as C buffer)
  __shared__ unsigned short B[128 * 128];  // 32KB
  const int tid = threadIdx.x;
  const int lane = tid & 63;
  const int w = tid >> 6;
  const int nb = blockIdx.x * 128;

  // stage B: 2048 16B units, linear global -> swizzled LDS
  {
    int u = tid;
#pragma unroll
    for (int i = 0; i < 8; ++i, u += 256) {
      int n = u >> 4, slot = u & 15;
      uint4 v = *(const uint4*)((const char*)Wt + u * 16);
      int addr = n * 256 + ((slot * 16) ^ ((n & 7) << 4));
      *(uint4*)((char*)B + addr) = v;
    }
  }
  // stage A: 4096 float4 units of x, convert to bf16, swizzled LDS write
  {
    int f = tid;
#pragma unroll
    for (int i = 0; i < 16; ++i, f += 256) {
      int row = f >> 5, c4 = f & 31;
      int node = nb + row;
      float4 v = make_float4(0.f, 0.f, 0.f, 0.f);
      if (node < NN) v = *(const float4*)(x + (long)node * CIN + c4 * 4);
      uint2 p;
      p.x = (unsigned)f2b(v.x) | ((unsigned)f2b(v.y) << 16);
      p.y = (unsigned)f2b(v.z) | ((unsigned)f2b(v.w) << 16);
      int base16 = row * 256 + (((c4 >> 1) << 4) ^ ((row & 7) << 4));
      *(uint2*)((char*)A + base16 + (c4 & 1) * 8) = p;
    }
  }
  __syncthreads();

  const int m0 = w * 32;
  f32x4 acc[2][8];
#pragma unroll
  for (int mt = 0; mt < 2; ++mt)
#pragma unroll
    for (int nt = 0; nt < 8; ++nt) acc[mt][nt] = (f32x4){0.f, 0.f, 0.f, 0.f};

#pragma unroll
  for (int ks = 0; ks < 4; ++ks) {
    const int kb2 = (ks * 32 + (lane >> 4) * 8) * 2;  // byte offset of k run
    const int r0 = m0 + (lane & 15);
    const int r1 = r0 + 16;
    s16x8 a0 = *(const s16x8*)((char*)A + r0 * 256 + (kb2 ^ ((r0 & 7) << 4)));
    s16x8 a1 = *(const s16x8*)((char*)A + r1 * 256 + (kb2 ^ ((r1 & 7) << 4)));
#pragma unroll
    for (int nt = 0; nt < 8; ++nt) {
      const int col = nt * 16 + (lane & 15);
      s16x8 b =
          *(const s16x8*)((char*)B + col * 256 + (kb2 ^ ((col & 7) << 4)));
      acc[0][nt] =
          __builtin_amdgcn_mfma_f32_16x16x32_bf16(a0, b, acc[0][nt], 0, 0, 0);
      acc[1][nt] =
          __builtin_amdgcn_mfma_f32_16x16x32_bf16(a1, b, acc[1][nt], 0, 0, 0);
    }
  }
  __syncthreads();  // done reading A; reuse as C

#pragma unroll
  for (int mt = 0; mt < 2; ++mt) {
    const int rowb = m0 + mt * 16 + (lane >> 4) * 4;
#pragma unroll
    for (int nt = 0; nt < 8; ++nt) {
      const int col = nt * 16 + (lane & 15);
#pragma unroll
      for (int r = 0; r < 4; ++r)
        *((unsigned short*)A + (rowb + r) * 128 + col) = f2b(acc[mt][nt][r]);
    }
  }
  __syncthreads();

  // coalesced store: 2048 16B units; slot<8 -> xl, else xr
  {
    int u = tid;
#pragma unroll
    for (int i = 0; i < 8; ++i, u += 256) {
      int row = u >> 4, slot = u & 15;
      int node = nb + row;
      if (node < NN) {
        uint4 v = *(const uint4*)((const char*)A + row * 256 + slot * 16);
        if (slot < 8)
          *(uint4*)((char*)xl + (long)node * 128 + slot * 16) = v;
        else
          *(uint4*)((char*)xr + (long)node * 128 + (slot - 8) * 16) = v;
      }
    }
  }
}

// ---------------------------------------------------------------------------
// Phase A: direct bucket scatter. 1.6M int atomics over 3125 counters;
// bucket frontier lines (~200KB) stay L2-hot. Packed (s<<5)|(t&31).
// ---------------------------------------------------------------------------
__global__ __launch_bounds__(256) void k_bucket(
    const int* __restrict__ ei, int* __restrict__ gcur,
    unsigned int* __restrict__ buckets) {
  const int j = blockIdx.x * 256 + threadIdx.x;
  if (j >= EE) return;
  const int s = ei[j];
  const int t = ei[EE + j];
  const int b = t >> 5;
  const int p = atomicAdd(gcur + b, 1);
  if (p < CAP)
    buckets[(long)b * CAP + p] = ((unsigned)s << 5) | (unsigned)(t & 31);
}

// ---------------------------------------------------------------------------
// Phase B fused pull (bf16 xl/xr): LDS counting sort, then 16 lanes/target
// (4 ch each, ushort4=8B gathers), edge loop unrolled x2. No max-subtract
// (|e| small; identical after normalization). Pool via LDS partials.
// ---------------------------------------------------------------------------
__global__ __launch_bounds__(256) void k_pull2(
    const int* __restrict__ gcnt, const unsigned int* __restrict__ buckets,
    const unsigned short* __restrict__ xl, const unsigned short* __restrict__ xr,
    const float* __restrict__ att, const float* __restrict__ bias,
    const int* __restrict__ batch, float* __restrict__ pooled,
    float* __restrict__ cnt) {
  __shared__ unsigned int staged[CAP];
  __shared__ int lds_src[CAP];
  __shared__ int hist[BSZ];
  __shared__ int starts[BSZ + 1], cur[BSZ];
  __shared__ float pool2[2][HID];
  __shared__ float cnt2[2];
  const int tid = threadIdx.x;
  const int b = blockIdx.x;
  const int t0 = b << 5;
  const int ecnt = min(gcnt[b], CAP);

  if (tid < BSZ) hist[tid] = 0;
  if (tid < 2 * HID) ((float*)pool2)[tid] = 0.f;
  if (tid < 2) cnt2[tid] = 0.f;
  __syncthreads();

  for (int i = tid; i < ecnt; i += 256) {
    unsigned v = buckets[(long)b * CAP + i];
    staged[i] = v;
    atomicAdd(&hist[v & 31u], 1);
  }
  __syncthreads();

  if (tid < BSZ) {
    int v = hist[tid];
    int sum = v;
#pragma unroll
    for (int off = 1; off < BSZ; off <<= 1) {
      int t = __shfl_up(sum, off, 64);
      if (tid >= off) sum += t;
    }
    starts[tid] = sum - v;
    cur[tid] = sum - v;
    if (tid == BSZ - 1) starts[BSZ] = sum;
  }
  __syncthreads();

  for (int i = tid; i < ecnt; i += 256) {
    unsigned v = staged[i];
    int d = v & 31u;
    int p = atomicAdd(&cur[d], 1);
    lds_src[p] = (int)(v >> 5);
  }
  __syncthreads();

  const int g = tid & 15;
  const int grp = tid >> 4;
  const float4 a4 = *(const float4*)(att + g * 4);
  const float4 b4 = *(const float4*)(bias + g * 4);
  const int g0 = batch[t0];

#pragma unroll
  for (int rep = 0; rep < 2; ++rep) {
    const int d = grp * 2 + rep;
    const int n = t0 + d;
    const ushort4 ut = *(const ushort4*)(xr + (long)n * HID + g * 4);
    const float xtx = b2f(ut.x), xty = b2f(ut.y);
    const float xtz = b2f(ut.z), xtw = b2f(ut.w);
    float4 acc = make_float4(0.f, 0.f, 0.f, 0.f);
    float den = 0.f;
    const int e0 = starts[d], e1 = starts[d + 1];
    int e = e0;
    for (; e + 1 < e1; e += 2) {  // x2 unroll: two gathers in flight
      const int s0 = lds_src[e];
      const int s1 = lds_src[e + 1];
      const ushort4 u0 = *(const ushort4*)(xl + (long)s0 * HID + g * 4);
      const ushort4 u1 = *(const ushort4*)(xl + (long)s1 * HID + g * 4);
      const float x0x = b2f(u0.x), x0y = b2f(u0.y);
      const float x0z = b2f(u0.z), x0w = b2f(u0.w);
      const float x1x = b2f(u1.x), x1y = b2f(u1.y);
      const float x1z = b2f(u1.z), x1w = b2f(u1.w);
      float zx0 = x0x + xtx, zy0 = x0y + xty, zz0 = x0z + xtz, zw0 = x0w + xtw;
      float zx1 = x1x + xtx, zy1 = x1y + xty, zz1 = x1z + xtz, zw1 = x1w + xtw;
      zx0 = zx0 > 0.f ? zx0 : 0.2f * zx0;
      zy0 = zy0 > 0.f ? zy0 : 0.2f * zy0;
      zz0 = zz0 > 0.f ? zz0 : 0.2f * zz0;
      zw0 = zw0 > 0.f ? zw0 : 0.2f * zw0;
      zx1 = zx1 > 0.f ? zx1 : 0.2f * zx1;
      zy1 = zy1 > 0.f ? zy1 : 0.2f * zy1;
      zz1 = zz1 > 0.f ? zz1 : 0.2f * zz1;
      zw1 = zw1 > 0.f ? zw1 : 0.2f * zw1;
      float p0 = zx0 * a4.x + zy0 * a4.y + zz0 * a4.z + zw0 * a4.w;
      float p1 = zx1 * a4.x + zy1 * a4.y + zz1 * a4.z + zw1 * a4.w;
      p0 += __shfl_xor(p0, 1, 16);
      p1 += __shfl_xor(p1, 1, 16);
      p0 += __shfl_xor(p0, 2, 16);
      p1 += __shfl_xor(p1, 2, 16);
      p0 += __shfl_xor(p0, 4, 16);
      p1 += __shfl_xor(p1, 4, 16);
      p0 += __shfl_xor(p0, 8, 16);
      p1 += __shfl_xor(p1, 8, 16);
      const float a0 = __expf(p0);
      const float a1 = __expf(p1);
      den += a0 + a1;
      acc.x = fmaf(a0, x0x, acc.x);
      acc.y = fmaf(a0, x0y, acc.y);
      acc.z = fmaf(a0, x0z, acc.z);
      acc.w = fmaf(a0, x0w, acc.w);
      acc.x = fmaf(a1, x1x, acc.x);
      acc.y = fmaf(a1, x1y, acc.y);
      acc.z = fmaf(a1, x1z, acc.z);
      acc.w = fmaf(a1, x1w, acc.w);
    }
    if (e < e1) {  // tail
      const int s0 = lds_src[e];
      const ushort4 u0 = *(const ushort4*)(xl + (long)s0 * HID + g * 4);
      const float x0x = b2f(u0.x), x0y = b2f(u0.y);
      const float x0z = b2f(u0.z), x0w = b2f(u0.w);
      float zx0 = x0x + xtx, zy0 = x0y + xty, zz0 = x0z + xtz, zw0 = x0w + xtw;
      zx0 = zx0 > 0.f ? zx0 : 0.2f * zx0;
      zy0 = zy0 > 0.f ? zy0 : 0.2f * zy0;
      zz0 = zz0 > 0.f ? zz0 : 0.2f * zz0;
      zw0 = zw0 > 0.f ? zw0 : 0.2f * zw0;
      float p0 = zx0 * a4.x + zy0 * a4.y + zz0 * a4.z + zw0 * a4.w;
      p0 += __shfl_xor(p0, 1, 16);
      p0 += __shfl_xor(p0, 2, 16);
      p0 += __shfl_xor(p0, 4, 16);
      p0 += __shfl_xor(p0, 8, 16);
      const float a0 = __expf(p0);
      den += a0;
      acc.x = fmaf(a0, x0x, acc.x);
      acc.y = fmaf(a0, x0y, acc.y);
      acc.z = fmaf(a0, x0z, acc.z);
      acc.w = fmaf(a0, x0w, acc.w);
    }
    const float inv = 1.f / (den + 1e-16f);
    float4 v4 = make_float4(fmaf(acc.x, inv, b4.x), fmaf(acc.y, inv, b4.y),
                            fmaf(acc.z, inv, b4.z), fmaf(acc.w, inv, b4.w));
    const int gr = batch[n];
    const int idx = gr - g0;
    if (idx >= 0 && idx < 2) {
      atomicAdd(&pool2[idx][g * 4 + 0], v4.x);
      atomicAdd(&pool2[idx][g * 4 + 1], v4.y);
      atomicAdd(&pool2[idx][g * 4 + 2], v4.z);
      atomicAdd(&pool2[idx][g * 4 + 3], v4.w);
      if (g == 0) atomicAdd(&cnt2[idx], 1.f);
    } else {  // safety net
      atomicAdd(pooled + gr * HID + g * 4 + 0, v4.x);
      atomicAdd(pooled + gr * HID + g * 4 + 1, v4.y);
      atomicAdd(pooled + gr * HID + g * 4 + 2, v4.z);
      atomicAdd(pooled + gr * HID + g * 4 + 3, v4.w);
      if (g == 0) atomicAdd(cnt + gr, 1.f);
    }
  }
  __syncthreads();
  if (tid < 2 * HID) {
    const int which = tid >> 6, c = tid & 63;
    const int gg = g0 + which;
    const float val = pool2[which][c];
    if (gg < NG && val != 0.f) atomicAdd(pooled + gg * HID + c, val);
  }
  if (tid < 2) {
    const int gg = g0 + tid;
    if (gg < NG && cnt2[tid] != 0.f) atomicAdd(cnt + gg, cnt2[tid]);
  }
}

// ---------------------------------------------------------------------------
// K4: pooled mean -> leaky(0.01) -> @fc_w + fc_b
// ---------------------------------------------------------------------------
__global__ void k_final(const float* __restrict__ pooled,
                        const float* __restrict__ cnt,
                        const float* __restrict__ fc_w,
                        const float* __restrict__ fc_b,
                        float* __restrict__ out) {
  const int tid = threadIdx.x;
  if (tid >= NG * NOUT) return;
  const int gr = tid / NOUT, o = tid % NOUT;
  const float cg = fmaxf(cnt[gr], 1.0f);
  float acc = fc_b[o];
#pragma unroll 8
  for (int h = 0; h < HID; ++h) {
    float pv = pooled[gr * HID + h] / cg;
    float hv = pv > 0.f ? pv : 0.01f * pv;
    acc = fmaf(hv, fc_w[h * NOUT + o], acc);
  }
  out[gr * NOUT + o] = acc;
}

extern "C" void kernel_launch(void* const* d_in, const int* in_sizes, int n_in,
                              void* d_out, int out_size, void* d_ws,
                              size_t ws_size, hipStream_t stream) {
  const float* x = (const float*)d_in[0];
  const float* Wl = (const float*)d_in[1];
  const float* Wr = (const float*)d_in[2];
  const float* att = (const float*)d_in[3];
  const float* bias = (const float*)d_in[4];
  const float* fc_w = (const float*)d_in[5];
  const float* fc_b = (const float*)d_in[6];
  const int* ei = (const int*)d_in[7];
  const int* batch = (const int*)d_in[8];
  float* out = (float*)d_out;

  unsigned short* xl = (unsigned short*)d_ws;            // NN*HID bf16
  unsigned short* xr = xl + (long)NN * HID;              // NN*HID bf16
  unsigned short* Wt = xr + (long)NN * HID;              // 128*128 bf16
  unsigned int* buckets = (unsigned int*)(Wt + 128 * 128);  // NB*CAP u32
  int* gcur = (int*)(buckets + (long)NB * CAP);          // NB
  float* pooled = (float*)(gcur + NB);                   // NG*HID
  float* cnt = pooled + NG * HID;                        // NG

  hipMemsetAsync(gcur, 0, (size_t)(NB + NG * HID + NG) * sizeof(int), stream);

  k_prep<<<8, 256, 0, stream>>>(Wl, Wr, Wt);
  k_gemm<<<(NN + 127) / 128, 256, 0, stream>>>(x, Wt, xl, xr);
  k_bucket<<<(EE + 255) / 256, 256, 0, stream>>>(ei, gcur, buckets);
  k_pull2<<<NB, 256, 0, stream>>>(gcur, buckets, xl, xr, att, bias, batch,
                                  pooled, cnt);
  k_final<<<1, NG * NOUT, 0, stream>>>(pooled, cnt, fc_w, fc_b, out);
}

// Round 7
// 255.141 us; speedup vs baseline: 1.3895x; 1.3895x over previous
//
#include <hip/hip_runtime.h>
#include <hip/hip_bf16.h>

#define NN 100000      // nodes
#define EE 1600000     // edges
#define CIN 128        // in channels
#define HID 64         // hidden
#define NG 64          // graphs
#define NOUT 10        // out channels
#define BSZ 32         // targets per fine bucket
#define NB 3125        // fine buckets actually used (ceil(NN/32))
#define NBA 3136       // fine bucket array size (196*16)
#define CAP 768        // fine bucket capacity (mean 512, +11 sigma)
#define NBC 196        // coarse buckets (512 targets each)
#define CCAP 9216      // coarse capacity (mean 8192, +11 sigma)

typedef short s16x8 __attribute__((ext_vector_type(8)));
typedef float f32x4 __attribute__((ext_vector_type(4)));

__device__ __forceinline__ unsigned short f2b(float f) {  // f32 -> bf16 RNE
  unsigned int b = __float_as_uint(f);
  return (unsigned short)((b + 0x7FFFu + ((b >> 16) & 1u)) >> 16);
}
__device__ __forceinline__ float b2f(unsigned short h) {  // bf16 -> f32 exact
  return __uint_as_float(((unsigned int)h) << 16);
}

// ---------------------------------------------------------------------------
// K0: W prep — Wt[n][k] = bf16(W[k][n]), n: 0-63 Wl cols, 64-127 Wr cols.
// ---------------------------------------------------------------------------
__global__ __launch_bounds__(256) void k_prep(const float* __restrict__ Wl,
                                              const float* __restrict__ Wr,
                                              unsigned short* __restrict__ Wt) {
  int flat = blockIdx.x * 2048 + threadIdx.x;
  for (int i = 0; i < 8; ++i, flat += 256) {
    int n = flat & 127, k = flat >> 7;
    float v = (n < 64) ? Wl[k * 64 + n] : Wr[k * 64 + (n - 64)];
    Wt[n * 128 + k] = f2b(v);
  }
}

// ---------------------------------------------------------------------------
// K1: [xl|xr] = bf16( x @ [Wl|Wr] ) via mfma_f32_16x16x32_bf16.
// (validated round 6: absmax 4.9e-4). 128x128 tile, 4 waves, XOR-swizzled LDS.
// ---------------------------------------------------------------------------
__global__ __launch_bounds__(256) void k_gemm(
    const float* __restrict__ x, const unsigned short* __restrict__ Wt,
    unsigned short* __restrict__ xl, unsigned short* __restrict__ xr) {
  __shared__ unsigned short A[128 * 128];  // 32KB (reused as C buffer)
  __shared__ unsigned short B[128 * 128];  // 32KB
  const int tid = threadIdx.x;
  const int lane = tid & 63;
  const int w = tid >> 6;
  const int nb = blockIdx.x * 128;

  {
    int u = tid;
#pragma unroll
    for (int i = 0; i < 8; ++i, u += 256) {
      int n = u >> 4, slot = u & 15;
      uint4 v = *(const uint4*)((const char*)Wt + u * 16);
      int addr = n * 256 + ((slot * 16) ^ ((n & 7) << 4));
      *(uint4*)((char*)B + addr) = v;
    }
  }
  {
    int f = tid;
#pragma unroll
    for (int i = 0; i < 16; ++i, f += 256) {
      int row = f >> 5, c4 = f & 31;
      int node = nb + row;
      float4 v = make_float4(0.f, 0.f, 0.f, 0.f);
      if (node < NN) v = *(const float4*)(x + (long)node * CIN + c4 * 4);
      uint2 p;
      p.x = (unsigned)f2b(v.x) | ((unsigned)f2b(v.y) << 16);
      p.y = (unsigned)f2b(v.z) | ((unsigned)f2b(v.w) << 16);
      int base16 = row * 256 + (((c4 >> 1) << 4) ^ ((row & 7) << 4));
      *(uint2*)((char*)A + base16 + (c4 & 1) * 8) = p;
    }
  }
  __syncthreads();

  const int m0 = w * 32;
  f32x4 acc[2][8];
#pragma unroll
  for (int mt = 0; mt < 2; ++mt)
#pragma unroll
    for (int nt = 0; nt < 8; ++nt) acc[mt][nt] = (f32x4){0.f, 0.f, 0.f, 0.f};

#pragma unroll
  for (int ks = 0; ks < 4; ++ks) {
    const int kb2 = (ks * 32 + (lane >> 4) * 8) * 2;
    const int r0 = m0 + (lane & 15);
    const int r1 = r0 + 16;
    s16x8 a0 = *(const s16x8*)((char*)A + r0 * 256 + (kb2 ^ ((r0 & 7) << 4)));
    s16x8 a1 = *(const s16x8*)((char*)A + r1 * 256 + (kb2 ^ ((r1 & 7) << 4)));
#pragma unroll
    for (int nt = 0; nt < 8; ++nt) {
      const int col = nt * 16 + (lane & 15);
      s16x8 b =
          *(const s16x8*)((char*)B + col * 256 + (kb2 ^ ((col & 7) << 4)));
      acc[0][nt] =
          __builtin_amdgcn_mfma_f32_16x16x32_bf16(a0, b, acc[0][nt], 0, 0, 0);
      acc[1][nt] =
          __builtin_amdgcn_mfma_f32_16x16x32_bf16(a1, b, acc[1][nt], 0, 0, 0);
    }
  }
  __syncthreads();

#pragma unroll
  for (int mt = 0; mt < 2; ++mt) {
    const int rowb = m0 + mt * 16 + (lane >> 4) * 4;
#pragma unroll
    for (int nt = 0; nt < 8; ++nt) {
      const int col = nt * 16 + (lane & 15);
#pragma unroll
      for (int r = 0; r < 4; ++r)
        *((unsigned short*)A + (rowb + r) * 128 + col) = f2b(acc[mt][nt][r]);
    }
  }
  __syncthreads();

  {
    int u = tid;
#pragma unroll
    for (int i = 0; i < 8; ++i, u += 256) {
      int row = u >> 4, slot = u & 15;
      int node = nb + row;
      if (node < NN) {
        uint4 v = *(const uint4*)((const char*)A + row * 256 + slot * 16);
        if (slot < 8)
          *(uint4*)((char*)xl + (long)node * 128 + slot * 16) = v;
        else
          *(uint4*)((char*)xr + (long)node * 128 + (slot - 8) * 16) = v;
      }
    }
  }
}

// ---------------------------------------------------------------------------
// Partition level 1: coarse buckets (512 targets). LDS histogram + bulk
// reservation -> each block writes runs of ~21 entries (full lines, single
// writer except boundaries). Payload (s<<9)|(t&511).
// ---------------------------------------------------------------------------
__global__ __launch_bounds__(256) void k_coarse(const int* __restrict__ ei,
                                                int* __restrict__ gcurc,
                                                unsigned int* __restrict__ coarse) {
  __shared__ int hist[NBC], lbase[NBC], cur[NBC];
  const int tid = threadIdx.x;
  const int base = blockIdx.x * 4096;
  for (int b = tid; b < NBC; b += 256) hist[b] = 0;
  __syncthreads();
#pragma unroll
  for (int i = 0; i < 16; ++i) {
    int j = base + i * 256 + tid;
    if (j < EE) atomicAdd(&hist[ei[EE + j] >> 9], 1);
  }
  __syncthreads();
  for (int b = tid; b < NBC; b += 256) {
    int c = hist[b];
    lbase[b] = c ? atomicAdd(gcurc + b, c) : 0;
    cur[b] = 0;
  }
  __syncthreads();
#pragma unroll
  for (int i = 0; i < 16; ++i) {
    int j = base + i * 256 + tid;
    if (j < EE) {
      int s = ei[j];
      int t = ei[EE + j];
      int cb = t >> 9;
      int p = lbase[cb] + atomicAdd(&cur[cb], 1);
      if (p < CCAP)
        coarse[(long)cb * CCAP + p] = ((unsigned)s << 9) | (unsigned)(t & 511);
    }
  }
}

// ---------------------------------------------------------------------------
// Partition level 2: one block per coarse bucket = SOLE writer of its 16 fine
// buckets (no atomics to global, no cross-XCD line sharing, coalesced runs).
// Full 512-way counting sort in LDS; also emits per-target start offsets
// (sc16) and counts (gcnt) so pull2 needs no sort phase at all.
// ---------------------------------------------------------------------------
__global__ __launch_bounds__(256) void k_fine(
    const int* __restrict__ gcurc, const unsigned int* __restrict__ coarse,
    unsigned int* __restrict__ buckets, unsigned short* __restrict__ sc16,
    int* __restrict__ gcnt) {
  __shared__ unsigned int staged[CCAP];  // 36KB
  __shared__ int hist[512], sc[512], cur[512];
  __shared__ int ex32[16], csum[4], coffs[4];
  const int tid = threadIdx.x;
  const int c = blockIdx.x;
  const int ecnt = min(gcurc[c], CCAP);

  for (int i = tid; i < 512; i += 256) hist[i] = 0;
  __syncthreads();
  for (int i = tid; i < ecnt; i += 256) {
    unsigned v = coarse[(long)c * CCAP + i];
    staged[i] = v;
    atomicAdd(&hist[v & 511u], 1);
  }
  __syncthreads();

  // inclusive scan over 512: 4 waves x 2 chunks of 64 (shfl), then offsets
  {
    const int w = tid >> 6, lane = tid & 63;
    const int iA = w * 128 + lane, iB = iA + 64;
    int sA = hist[iA], sB = hist[iB];
#pragma unroll
    for (int off = 1; off < 64; off <<= 1) {
      int t1 = __shfl_up(sA, off, 64);
      int t2 = __shfl_up(sB, off, 64);
      if (lane >= off) { sA += t1; sB += t2; }
    }
    int tA = __shfl(sA, 63, 64);
    int tB = __shfl(sB, 63, 64);
    sc[iA] = sA;
    sc[iB] = sB + tA;
    if (lane == 0) csum[w] = tA + tB;
    __syncthreads();
    if (tid == 0) {
      int r = 0;
#pragma unroll
      for (int q = 0; q < 4; ++q) { coffs[q] = r; r += csum[q]; }
    }
    __syncthreads();
    sc[iA] += coffs[w];
    sc[iB] += coffs[w];
  }
  __syncthreads();

  if (tid < 16) ex32[tid] = sc[tid * 32] - hist[tid * 32];
  __syncthreads();
  for (int i = tid; i < 512; i += 256) {
    int f = i >> 5;
    int ex = sc[i] - hist[i];
    cur[i] = ex;
    int rel = ex - ex32[f];
    if (rel > CAP) rel = CAP;
    sc16[((long)c * 16 + f) * 32 + (i & 31)] = (unsigned short)rel;
  }
  if (tid < 16) {
    int fb = sc[tid * 32 + 31] - ex32[tid];
    gcnt[c * 16 + tid] = fb > CAP ? CAP : fb;
  }
  __syncthreads();
  for (int i = tid; i < ecnt; i += 256) {
    unsigned v = staged[i];
    int t9 = v & 511u;
    int p = atomicAdd(&cur[t9], 1);
    int rel = p - ex32[t9 >> 5];
    if (rel < CAP)
      buckets[((long)c * 16 + (t9 >> 5)) * CAP + rel] = v >> 9;  // plain src id
  }
}

// ---------------------------------------------------------------------------
// Pull (bf16 xl/xr, pre-sorted edges): 16 lanes/target, 2 targets/group,
// x2 edge unroll. No LDS sort, ~0.5KB LDS -> full occupancy. No max-subtract
// (|e| small; identical after normalization). Pool via LDS partials.
// ---------------------------------------------------------------------------
__global__ __launch_bounds__(256) void k_pull2(
    const int* __restrict__ gcnt, const unsigned int* __restrict__ buckets,
    const unsigned short* __restrict__ sc16,
    const unsigned short* __restrict__ xl,
    const unsigned short* __restrict__ xr, const float* __restrict__ att,
    const float* __restrict__ bias, const int* __restrict__ batch,
    float* __restrict__ pooled, float* __restrict__ cnt) {
  __shared__ float pool2[2][HID];
  __shared__ float cnt2[2];
  const int tid = threadIdx.x;
  const int b = blockIdx.x;
  const int t0 = b << 5;
  if (tid < 2 * HID) ((float*)pool2)[tid] = 0.f;
  if (tid < 2) cnt2[tid] = 0.f;
  __syncthreads();

  const int g = tid & 15;
  const int grp = tid >> 4;
  const float4 a4 = *(const float4*)(att + g * 4);
  const float4 b4 = *(const float4*)(bias + g * 4);
  const int g0 = batch[t0];

#pragma unroll
  for (int rep = 0; rep < 2; ++rep) {
    const int d = grp * 2 + rep;
    const int n = t0 + d;
    const ushort4 ut = *(const ushort4*)(xr + (long)n * HID + g * 4);
    const float xtx = b2f(ut.x), xty = b2f(ut.y);
    const float xtz = b2f(ut.z), xtw = b2f(ut.w);
    float4 acc = make_float4(0.f, 0.f, 0.f, 0.f);
    float den = 0.f;
    const int e0 = sc16[(long)b * 32 + d];
    const int e1 = (d < 31) ? (int)sc16[(long)b * 32 + d + 1] : gcnt[b];
    int e = e0;
    for (; e + 1 < e1; e += 2) {  // x2 unroll: two gathers in flight
      const int s0 = buckets[(long)b * CAP + e];
      const int s1 = buckets[(long)b * CAP + e + 1];
      const ushort4 u0 = *(const ushort4*)(xl + (long)s0 * HID + g * 4);
      const ushort4 u1 = *(const ushort4*)(xl + (long)s1 * HID + g * 4);
      const float x0x = b2f(u0.x), x0y = b2f(u0.y);
      const float x0z = b2f(u0.z), x0w = b2f(u0.w);
      const float x1x = b2f(u1.x), x1y = b2f(u1.y);
      const float x1z = b2f(u1.z), x1w = b2f(u1.w);
      float zx0 = x0x + xtx, zy0 = x0y + xty, zz0 = x0z + xtz, zw0 = x0w + xtw;
      float zx1 = x1x + xtx, zy1 = x1y + xty, zz1 = x1z + xtz, zw1 = x1w + xtw;
      zx0 = zx0 > 0.f ? zx0 : 0.2f * zx0;
      zy0 = zy0 > 0.f ? zy0 : 0.2f * zy0;
      zz0 = zz0 > 0.f ? zz0 : 0.2f * zz0;
      zw0 = zw0 > 0.f ? zw0 : 0.2f * zw0;
      zx1 = zx1 > 0.f ? zx1 : 0.2f * zx1;
      zy1 = zy1 > 0.f ? zy1 : 0.2f * zy1;
      zz1 = zz1 > 0.f ? zz1 : 0.2f * zz1;
      zw1 = zw1 > 0.f ? zw1 : 0.2f * zw1;
      float p0 = zx0 * a4.x + zy0 * a4.y + zz0 * a4.z + zw0 * a4.w;
      float p1 = zx1 * a4.x + zy1 * a4.y + zz1 * a4.z + zw1 * a4.w;
      p0 += __shfl_xor(p0, 1, 16);
      p1 += __shfl_xor(p1, 1, 16);
      p0 += __shfl_xor(p0, 2, 16);
      p1 += __shfl_xor(p1, 2, 16);
      p0 += __shfl_xor(p0, 4, 16);
      p1 += __shfl_xor(p1, 4, 16);
      p0 += __shfl_xor(p0, 8, 16);
      p1 += __shfl_xor(p1, 8, 16);
      const float a0 = __expf(p0);
      const float a1 = __expf(p1);
      den += a0 + a1;
      acc.x = fmaf(a0, x0x, acc.x);
      acc.y = fmaf(a0, x0y, acc.y);
      acc.z = fmaf(a0, x0z, acc.z);
      acc.w = fmaf(a0, x0w, acc.w);
      acc.x = fmaf(a1, x1x, acc.x);
      acc.y = fmaf(a1, x1y, acc.y);
      acc.z = fmaf(a1, x1z, acc.z);
      acc.w = fmaf(a1, x1w, acc.w);
    }
    if (e < e1) {  // tail
      const int s0 = buckets[(long)b * CAP + e];
      const ushort4 u0 = *(const ushort4*)(xl + (long)s0 * HID + g * 4);
      const float x0x = b2f(u0.x), x0y = b2f(u0.y);
      const float x0z = b2f(u0.z), x0w = b2f(u0.w);
      float zx0 = x0x + xtx, zy0 = x0y + xty, zz0 = x0z + xtz, zw0 = x0w + xtw;
      zx0 = zx0 > 0.f ? zx0 : 0.2f * zx0;
      zy0 = zy0 > 0.f ? zy0 : 0.2f * zy0;
      zz0 = zz0 > 0.f ? zz0 : 0.2f * zz0;
      zw0 = zw0 > 0.f ? zw0 : 0.2f * zw0;
      float p0 = zx0 * a4.x + zy0 * a4.y + zz0 * a4.z + zw0 * a4.w;
      p0 += __shfl_xor(p0, 1, 16);
      p0 += __shfl_xor(p0, 2, 16);
      p0 += __shfl_xor(p0, 4, 16);
      p0 += __shfl_xor(p0, 8, 16);
      const float a0 = __expf(p0);
      den += a0;
      acc.x = fmaf(a0, x0x, acc.x);
      acc.y = fmaf(a0, x0y, acc.y);
      acc.z = fmaf(a0, x0z, acc.z);
      acc.w = fmaf(a0, x0w, acc.w);
    }
    const float inv = 1.f / (den + 1e-16f);
    float4 v4 = make_float4(fmaf(acc.x, inv, b4.x), fmaf(acc.y, inv, b4.y),
                            fmaf(acc.z, inv, b4.z), fmaf(acc.w, inv, b4.w));
    const int gr = batch[n];
    const int idx = gr - g0;
    if (idx >= 0 && idx < 2) {
      atomicAdd(&pool2[idx][g * 4 + 0], v4.x);
      atomicAdd(&pool2[idx][g * 4 + 1], v4.y);
      atomicAdd(&pool2[idx][g * 4 + 2], v4.z);
      atomicAdd(&pool2[idx][g * 4 + 3], v4.w);
      if (g == 0) atomicAdd(&cnt2[idx], 1.f);
    } else {  // safety net
      atomicAdd(pooled + gr * HID + g * 4 + 0, v4.x);
      atomicAdd(pooled + gr * HID + g * 4 + 1, v4.y);
      atomicAdd(pooled + gr * HID + g * 4 + 2, v4.z);
      atomicAdd(pooled + gr * HID + g * 4 + 3, v4.w);
      if (g == 0) atomicAdd(cnt + gr, 1.f);
    }
  }
  __syncthreads();
  if (tid < 2 * HID) {
    const int which = tid >> 6, c = tid & 63;
    const int gg = g0 + which;
    const float val = pool2[which][c];
    if (gg < NG && val != 0.f) atomicAdd(pooled + gg * HID + c, val);
  }
  if (tid < 2) {
    const int gg = g0 + tid;
    if (gg < NG && cnt2[tid] != 0.f) atomicAdd(cnt + gg, cnt2[tid]);
  }
}

// ---------------------------------------------------------------------------
// K4: pooled mean -> leaky(0.01) -> @fc_w + fc_b
// ---------------------------------------------------------------------------
__global__ void k_final(const float* __restrict__ pooled,
                        const float* __restrict__ cnt,
                        const float* __restrict__ fc_w,
                        const float* __restrict__ fc_b,
                        float* __restrict__ out) {
  const int tid = threadIdx.x;
  if (tid >= NG * NOUT) return;
  const int gr = tid / NOUT, o = tid % NOUT;
  const float cg = fmaxf(cnt[gr], 1.0f);
  float acc = fc_b[o];
#pragma unroll 8
  for (int h = 0; h < HID; ++h) {
    float pv = pooled[gr * HID + h] / cg;
    float hv = pv > 0.f ? pv : 0.01f * pv;
    acc = fmaf(hv, fc_w[h * NOUT + o], acc);
  }
  out[gr * NOUT + o] = acc;
}

extern "C" void kernel_launch(void* const* d_in, const int* in_sizes, int n_in,
                              void* d_out, int out_size, void* d_ws,
                              size_t ws_size, hipStream_t stream) {
  const float* x = (const float*)d_in[0];
  const float* Wl = (const float*)d_in[1];
  const float* Wr = (const float*)d_in[2];
  const float* att = (const float*)d_in[3];
  const float* bias = (const float*)d_in[4];
  const float* fc_w = (const float*)d_in[5];
  const float* fc_b = (const float*)d_in[6];
  const int* ei = (const int*)d_in[7];
  const int* batch = (const int*)d_in[8];
  float* out = (float*)d_out;

  char* w = (char*)d_ws;
  unsigned short* xl = (unsigned short*)w;            w += (long)NN * HID * 2;
  unsigned short* xr = (unsigned short*)w;            w += (long)NN * HID * 2;
  unsigned short* Wt = (unsigned short*)w;            w += 128 * 128 * 2;
  unsigned int* coarse = (unsigned int*)w;            w += (long)NBC * CCAP * 4;
  unsigned int* buckets = (unsigned int*)w;           w += (long)NBA * CAP * 4;
  unsigned short* sc16 = (unsigned short*)w;          w += (long)NBA * 32 * 2;
  int* gcnt = (int*)w;                                w += NBA * 4;
  int* gcurc = (int*)w;                               w += NBC * 4;
  float* pooled = (float*)w;                          w += NG * HID * 4;
  float* cnt = (float*)w;                             w += NG * 4;

  // zero gcurc + pooled + cnt (contiguous)
  hipMemsetAsync(gcurc, 0, (size_t)(NBC + NG * HID + NG) * sizeof(int),
                 stream);

  k_prep<<<8, 256, 0, stream>>>(Wl, Wr, Wt);
  k_gemm<<<(NN + 127) / 128, 256, 0, stream>>>(x, Wt, xl, xr);
  k_coarse<<<(EE + 4095) / 4096, 256, 0, stream>>>(ei, gcurc, coarse);
  k_fine<<<NBC, 256, 0, stream>>>(gcurc, coarse, buckets, sc16, gcnt);
  k_pull2<<<NB, 256, 0, stream>>>(gcnt, buckets, sc16, xl, xr, att, bias,
                                  batch, pooled, cnt);
  k_final<<<1, NG * NOUT, 0, stream>>>(pooled, cnt, fc_w, fc_b, out);
}

// Round 8
// 239.452 us; speedup vs baseline: 1.4805x; 1.0655x over previous
//
#include <hip/hip_runtime.h>
#include <hip/hip_bf16.h>

#define NN 100000      // nodes
#define EE 1600000     // edges
#define CIN 128        // in channels
#define HID 64         // hidden
#define NG 64          // graphs
#define NOUT 10        // out channels
#define BSZ 32         // targets per fine bucket
#define NB 3125        // fine buckets actually used (ceil(NN/32))
#define NBA 3136       // fine bucket array size (196*16)
#define CAP 768        // fine bucket capacity (mean 512, +11 sigma)
#define NBC 196        // coarse buckets (512 targets each)
#define CCAP 9216      // coarse capacity (mean 8192, +11 sigma)

typedef short s16x8 __attribute__((ext_vector_type(8)));
typedef float f32x4 __attribute__((ext_vector_type(4)));

__device__ __forceinline__ unsigned short f2b(float f) {  // f32 -> bf16 RNE
  unsigned int b = __float_as_uint(f);
  return (unsigned short)((b + 0x7FFFu + ((b >> 16) & 1u)) >> 16);
}
__device__ __forceinline__ float b2f_lo(unsigned int u) {
  return __uint_as_float(u << 16);
}
__device__ __forceinline__ float b2f_hi(unsigned int u) {
  return __uint_as_float(u & 0xFFFF0000u);
}

// ---------------------------------------------------------------------------
// K0: W prep — Wt[n][k] = bf16(W[k][n]), n: 0-63 Wl cols, 64-127 Wr cols.
// ---------------------------------------------------------------------------
__global__ __launch_bounds__(256) void k_prep(const float* __restrict__ Wl,
                                              const float* __restrict__ Wr,
                                              unsigned short* __restrict__ Wt) {
  int flat = blockIdx.x * 2048 + threadIdx.x;
  for (int i = 0; i < 8; ++i, flat += 256) {
    int n = flat & 127, k = flat >> 7;
    float v = (n < 64) ? Wl[k * 64 + n] : Wr[k * 64 + (n - 64)];
    Wt[n * 128 + k] = f2b(v);
  }
}

// ---------------------------------------------------------------------------
// K1: [xl|xr] = bf16( x @ [Wl|Wr] ) via mfma_f32_16x16x32_bf16.
// (validated round 6/7: absmax 4.9e-4). 128x128 tile, 4 waves, XOR-swizzled.
// ---------------------------------------------------------------------------
__global__ __launch_bounds__(256) void k_gemm(
    const float* __restrict__ x, const unsigned short* __restrict__ Wt,
    unsigned short* __restrict__ xl, unsigned short* __restrict__ xr) {
  __shared__ unsigned short A[128 * 128];  // 32KB (reused as C buffer)
  __shared__ unsigned short B[128 * 128];  // 32KB
  const int tid = threadIdx.x;
  const int lane = tid & 63;
  const int w = tid >> 6;
  const int nb = blockIdx.x * 128;

  {
    int u = tid;
#pragma unroll
    for (int i = 0; i < 8; ++i, u += 256) {
      int n = u >> 4, slot = u & 15;
      uint4 v = *(const uint4*)((const char*)Wt + u * 16);
      int addr = n * 256 + ((slot * 16) ^ ((n & 7) << 4));
      *(uint4*)((char*)B + addr) = v;
    }
  }
  {
    int f = tid;
#pragma unroll
    for (int i = 0; i < 16; ++i, f += 256) {
      int row = f >> 5, c4 = f & 31;
      int node = nb + row;
      float4 v = make_float4(0.f, 0.f, 0.f, 0.f);
      if (node < NN) v = *(const float4*)(x + (long)node * CIN + c4 * 4);
      uint2 p;
      p.x = (unsigned)f2b(v.x) | ((unsigned)f2b(v.y) << 16);
      p.y = (unsigned)f2b(v.z) | ((unsigned)f2b(v.w) << 16);
      int base16 = row * 256 + (((c4 >> 1) << 4) ^ ((row & 7) << 4));
      *(uint2*)((char*)A + base16 + (c4 & 1) * 8) = p;
    }
  }
  __syncthreads();

  const int m0 = w * 32;
  f32x4 acc[2][8];
#pragma unroll
  for (int mt = 0; mt < 2; ++mt)
#pragma unroll
    for (int nt = 0; nt < 8; ++nt) acc[mt][nt] = (f32x4){0.f, 0.f, 0.f, 0.f};

#pragma unroll
  for (int ks = 0; ks < 4; ++ks) {
    const int kb2 = (ks * 32 + (lane >> 4) * 8) * 2;
    const int r0 = m0 + (lane & 15);
    const int r1 = r0 + 16;
    s16x8 a0 = *(const s16x8*)((char*)A + r0 * 256 + (kb2 ^ ((r0 & 7) << 4)));
    s16x8 a1 = *(const s16x8*)((char*)A + r1 * 256 + (kb2 ^ ((r1 & 7) << 4)));
#pragma unroll
    for (int nt = 0; nt < 8; ++nt) {
      const int col = nt * 16 + (lane & 15);
      s16x8 b =
          *(const s16x8*)((char*)B + col * 256 + (kb2 ^ ((col & 7) << 4)));
      acc[0][nt] =
          __builtin_amdgcn_mfma_f32_16x16x32_bf16(a0, b, acc[0][nt], 0, 0, 0);
      acc[1][nt] =
          __builtin_amdgcn_mfma_f32_16x16x32_bf16(a1, b, acc[1][nt], 0, 0, 0);
    }
  }
  __syncthreads();

#pragma unroll
  for (int mt = 0; mt < 2; ++mt) {
    const int rowb = m0 + mt * 16 + (lane >> 4) * 4;
#pragma unroll
    for (int nt = 0; nt < 8; ++nt) {
      const int col = nt * 16 + (lane & 15);
#pragma unroll
      for (int r = 0; r < 4; ++r)
        *((unsigned short*)A + (rowb + r) * 128 + col) = f2b(acc[mt][nt][r]);
    }
  }
  __syncthreads();

  {
    int u = tid;
#pragma unroll
    for (int i = 0; i < 8; ++i, u += 256) {
      int row = u >> 4, slot = u & 15;
      int node = nb + row;
      if (node < NN) {
        uint4 v = *(const uint4*)((const char*)A + row * 256 + slot * 16);
        if (slot < 8)
          *(uint4*)((char*)xl + (long)node * 128 + slot * 16) = v;
        else
          *(uint4*)((char*)xr + (long)node * 128 + (slot - 8) * 16) = v;
      }
    }
  }
}

// ---------------------------------------------------------------------------
// Partition level 1: coarse buckets (512 targets). Single global read pass:
// (s,t) staged in registers across hist->reserve->scatter phases.
// ---------------------------------------------------------------------------
__global__ __launch_bounds__(256) void k_coarse(const int* __restrict__ ei,
                                                int* __restrict__ gcurc,
                                                unsigned int* __restrict__ coarse) {
  __shared__ int hist[NBC], lbase[NBC], cur[NBC];
  const int tid = threadIdx.x;
  const int base = blockIdx.x * 4096;
  int ss[16], tt[16];
  for (int b = tid; b < NBC; b += 256) hist[b] = 0;
#pragma unroll
  for (int i = 0; i < 16; ++i) {
    int j = base + i * 256 + tid;
    if (j < EE) {
      ss[i] = ei[j];
      tt[i] = ei[EE + j];
    } else {
      tt[i] = -1;
    }
  }
  __syncthreads();
#pragma unroll
  for (int i = 0; i < 16; ++i)
    if (tt[i] >= 0) atomicAdd(&hist[tt[i] >> 9], 1);
  __syncthreads();
  for (int b = tid; b < NBC; b += 256) {
    int c = hist[b];
    lbase[b] = c ? atomicAdd(gcurc + b, c) : 0;
    cur[b] = 0;
  }
  __syncthreads();
#pragma unroll
  for (int i = 0; i < 16; ++i) {
    if (tt[i] >= 0) {
      int cb = tt[i] >> 9;
      int p = lbase[cb] + atomicAdd(&cur[cb], 1);
      if (p < CCAP)
        coarse[(long)cb * CCAP + p] =
            ((unsigned)ss[i] << 9) | (unsigned)(tt[i] & 511);
    }
  }
}

// ---------------------------------------------------------------------------
// Partition level 2: one block per coarse bucket = SOLE writer of its 16 fine
// buckets. 512-way LDS counting sort; emits per-target offsets (sc16)+counts.
// ---------------------------------------------------------------------------
__global__ __launch_bounds__(256) void k_fine(
    const int* __restrict__ gcurc, const unsigned int* __restrict__ coarse,
    unsigned int* __restrict__ buckets, unsigned short* __restrict__ sc16,
    int* __restrict__ gcnt) {
  __shared__ unsigned int staged[CCAP];  // 36KB
  __shared__ int hist[512], sc[512], cur[512];
  __shared__ int ex32[16], csum[4], coffs[4];
  const int tid = threadIdx.x;
  const int c = blockIdx.x;
  const int ecnt = min(gcurc[c], CCAP);

  for (int i = tid; i < 512; i += 256) hist[i] = 0;
  __syncthreads();
  for (int i = tid; i < ecnt; i += 256) {
    unsigned v = coarse[(long)c * CCAP + i];
    staged[i] = v;
    atomicAdd(&hist[v & 511u], 1);
  }
  __syncthreads();

  {
    const int w = tid >> 6, lane = tid & 63;
    const int iA = w * 128 + lane, iB = iA + 64;
    int sA = hist[iA], sB = hist[iB];
#pragma unroll
    for (int off = 1; off < 64; off <<= 1) {
      int t1 = __shfl_up(sA, off, 64);
      int t2 = __shfl_up(sB, off, 64);
      if (lane >= off) { sA += t1; sB += t2; }
    }
    int tA = __shfl(sA, 63, 64);
    int tB = __shfl(sB, 63, 64);
    sc[iA] = sA;
    sc[iB] = sB + tA;
    if (lane == 0) csum[w] = tA + tB;
    __syncthreads();
    if (tid == 0) {
      int r = 0;
#pragma unroll
      for (int q = 0; q < 4; ++q) { coffs[q] = r; r += csum[q]; }
    }
    __syncthreads();
    sc[iA] += coffs[w];
    sc[iB] += coffs[w];
  }
  __syncthreads();

  if (tid < 16) ex32[tid] = sc[tid * 32] - hist[tid * 32];
  __syncthreads();
  for (int i = tid; i < 512; i += 256) {
    int f = i >> 5;
    int ex = sc[i] - hist[i];
    cur[i] = ex;
    int rel = ex - ex32[f];
    if (rel > CAP) rel = CAP;
    sc16[((long)c * 16 + f) * 32 + (i & 31)] = (unsigned short)rel;
  }
  if (tid < 16) {
    int fb = sc[tid * 32 + 31] - ex32[tid];
    gcnt[c * 16 + tid] = fb > CAP ? CAP : fb;
  }
  __syncthreads();
  for (int i = tid; i < ecnt; i += 256) {
    unsigned v = staged[i];
    int t9 = v & 511u;
    int p = atomicAdd(&cur[t9], 1);
    int rel = p - ex32[t9 >> 5];
    if (rel < CAP)
      buckets[((long)c * 16 + (t9 >> 5)) * CAP + rel] = v >> 9;  // src id
  }
}

// ---------------------------------------------------------------------------
// Pull: 8 lanes x 8 ch per target (uint4 16B gathers), 32 targets/block,
// 3-step shfl reduce, x2 edge unroll (16 gathers in flight per wave).
// No max-subtract (|e| small; identical after normalization). Pool via LDS.
// ---------------------------------------------------------------------------
__global__ __launch_bounds__(256) void k_pull2(
    const int* __restrict__ gcnt, const unsigned int* __restrict__ buckets,
    const unsigned short* __restrict__ sc16,
    const unsigned short* __restrict__ xl,
    const unsigned short* __restrict__ xr, const float* __restrict__ att,
    const float* __restrict__ bias, const int* __restrict__ batch,
    float* __restrict__ pooled, float* __restrict__ cnt) {
  __shared__ float pool2[2][HID];
  __shared__ float cnt2[2];
  const int tid = threadIdx.x;
  const int b = blockIdx.x;
  const int t0 = b << 5;
  if (tid < 2 * HID) ((float*)pool2)[tid] = 0.f;
  if (tid < 2) cnt2[tid] = 0.f;
  __syncthreads();

  const int l8 = tid & 7;   // channel octet
  const int d = tid >> 3;   // target within bucket (0..31)
  const int n = t0 + d;
  float av[8];
  {
    float4 alo = *(const float4*)(att + l8 * 8);
    float4 ahi = *(const float4*)(att + l8 * 8 + 4);
    av[0] = alo.x; av[1] = alo.y; av[2] = alo.z; av[3] = alo.w;
    av[4] = ahi.x; av[5] = ahi.y; av[6] = ahi.z; av[7] = ahi.w;
  }
  float xt[8];
  {
    uint4 ur = *(const uint4*)(xr + (long)n * HID + l8 * 8);
    xt[0] = b2f_lo(ur.x); xt[1] = b2f_hi(ur.x);
    xt[2] = b2f_lo(ur.y); xt[3] = b2f_hi(ur.y);
    xt[4] = b2f_lo(ur.z); xt[5] = b2f_hi(ur.z);
    xt[6] = b2f_lo(ur.w); xt[7] = b2f_hi(ur.w);
  }
  float acc[8] = {0.f, 0.f, 0.f, 0.f, 0.f, 0.f, 0.f, 0.f};
  float den = 0.f;
  const int e0 = sc16[(long)b * 32 + d];
  const int e1 = (d < 31) ? (int)sc16[(long)b * 32 + d + 1] : gcnt[b];
  const unsigned int* brow = buckets + (long)b * CAP;
  int e = e0;
  for (; e + 1 < e1; e += 2) {
    const int s0 = brow[e];
    const int s1 = brow[e + 1];
    const uint4 u0 = *(const uint4*)(xl + (long)s0 * HID + l8 * 8);
    const uint4 u1 = *(const uint4*)(xl + (long)s1 * HID + l8 * 8);
    float x0[8], x1[8];
    x0[0] = b2f_lo(u0.x); x0[1] = b2f_hi(u0.x);
    x0[2] = b2f_lo(u0.y); x0[3] = b2f_hi(u0.y);
    x0[4] = b2f_lo(u0.z); x0[5] = b2f_hi(u0.z);
    x0[6] = b2f_lo(u0.w); x0[7] = b2f_hi(u0.w);
    x1[0] = b2f_lo(u1.x); x1[1] = b2f_hi(u1.x);
    x1[2] = b2f_lo(u1.y); x1[3] = b2f_hi(u1.y);
    x1[4] = b2f_lo(u1.z); x1[5] = b2f_hi(u1.z);
    x1[6] = b2f_lo(u1.w); x1[7] = b2f_hi(u1.w);
    float p0 = 0.f, p1 = 0.f;
#pragma unroll
    for (int c = 0; c < 8; ++c) {
      float z0 = x0[c] + xt[c];
      float z1 = x1[c] + xt[c];
      z0 = z0 > 0.f ? z0 : 0.2f * z0;
      z1 = z1 > 0.f ? z1 : 0.2f * z1;
      p0 = fmaf(z0, av[c], p0);
      p1 = fmaf(z1, av[c], p1);
    }
    p0 += __shfl_xor(p0, 1, 8);
    p1 += __shfl_xor(p1, 1, 8);
    p0 += __shfl_xor(p0, 2, 8);
    p1 += __shfl_xor(p1, 2, 8);
    p0 += __shfl_xor(p0, 4, 8);
    p1 += __shfl_xor(p1, 4, 8);
    const float a0 = __expf(p0);
    const float a1 = __expf(p1);
    den += a0 + a1;
#pragma unroll
    for (int c = 0; c < 8; ++c) {
      acc[c] = fmaf(a0, x0[c], acc[c]);
      acc[c] = fmaf(a1, x1[c], acc[c]);
    }
  }
  if (e < e1) {  // tail
    const int s0 = brow[e];
    const uint4 u0 = *(const uint4*)(xl + (long)s0 * HID + l8 * 8);
    float x0[8];
    x0[0] = b2f_lo(u0.x); x0[1] = b2f_hi(u0.x);
    x0[2] = b2f_lo(u0.y); x0[3] = b2f_hi(u0.y);
    x0[4] = b2f_lo(u0.z); x0[5] = b2f_hi(u0.z);
    x0[6] = b2f_lo(u0.w); x0[7] = b2f_hi(u0.w);
    float p0 = 0.f;
#pragma unroll
    for (int c = 0; c < 8; ++c) {
      float z0 = x0[c] + xt[c];
      z0 = z0 > 0.f ? z0 : 0.2f * z0;
      p0 = fmaf(z0, av[c], p0);
    }
    p0 += __shfl_xor(p0, 1, 8);
    p0 += __shfl_xor(p0, 2, 8);
    p0 += __shfl_xor(p0, 4, 8);
    const float a0 = __expf(p0);
    den += a0;
#pragma unroll
    for (int c = 0; c < 8; ++c) acc[c] = fmaf(a0, x0[c], acc[c]);
  }
  const float inv = 1.f / (den + 1e-16f);
  const int gr = batch[n];
  const int idx = gr - batch[t0];
  float bv[8];
  {
    float4 blo = *(const float4*)(bias + l8 * 8);
    float4 bhi = *(const float4*)(bias + l8 * 8 + 4);
    bv[0] = blo.x; bv[1] = blo.y; bv[2] = blo.z; bv[3] = blo.w;
    bv[4] = bhi.x; bv[5] = bhi.y; bv[6] = bhi.z; bv[7] = bhi.w;
  }
  if (idx >= 0 && idx < 2) {
#pragma unroll
    for (int c = 0; c < 8; ++c)
      atomicAdd(&pool2[idx][l8 * 8 + c], fmaf(acc[c], inv, bv[c]));
    if (l8 == 0) atomicAdd(&cnt2[idx], 1.f);
  } else {  // safety net
#pragma unroll
    for (int c = 0; c < 8; ++c)
      atomicAdd(pooled + gr * HID + l8 * 8 + c, fmaf(acc[c], inv, bv[c]));
    if (l8 == 0) atomicAdd(cnt + gr, 1.f);
  }
  __syncthreads();
  const int g0 = batch[t0];
  if (tid < 2 * HID) {
    const int which = tid >> 6, c = tid & 63;
    const int gg = g0 + which;
    const float val = pool2[which][c];
    if (gg < NG && val != 0.f) atomicAdd(pooled + gg * HID + c, val);
  }
  if (tid < 2) {
    const int gg = g0 + tid;
    if (gg < NG && cnt2[tid] != 0.f) atomicAdd(cnt + gg, cnt2[tid]);
  }
}

// ---------------------------------------------------------------------------
// K4: pooled mean -> leaky(0.01) -> @fc_w + fc_b
// ---------------------------------------------------------------------------
__global__ void k_final(const float* __restrict__ pooled,
                        const float* __restrict__ cnt,
                        const float* __restrict__ fc_w,
                        const float* __restrict__ fc_b,
                        float* __restrict__ out) {
  const int tid = threadIdx.x;
  if (tid >= NG * NOUT) return;
  const int gr = tid / NOUT, o = tid % NOUT;
  const float cg = fmaxf(cnt[gr], 1.0f);
  float acc = fc_b[o];
#pragma unroll 8
  for (int h = 0; h < HID; ++h) {
    float pv = pooled[gr * HID + h] / cg;
    float hv = pv > 0.f ? pv : 0.01f * pv;
    acc = fmaf(hv, fc_w[h * NOUT + o], acc);
  }
  out[gr * NOUT + o] = acc;
}

extern "C" void kernel_launch(void* const* d_in, const int* in_sizes, int n_in,
                              void* d_out, int out_size, void* d_ws,
                              size_t ws_size, hipStream_t stream) {
  const float* x = (const float*)d_in[0];
  const float* Wl = (const float*)d_in[1];
  const float* Wr = (const float*)d_in[2];
  const float* att = (const float*)d_in[3];
  const float* bias = (const float*)d_in[4];
  const float* fc_w = (const float*)d_in[5];
  const float* fc_b = (const float*)d_in[6];
  const int* ei = (const int*)d_in[7];
  const int* batch = (const int*)d_in[8];
  float* out = (float*)d_out;

  char* w = (char*)d_ws;
  unsigned short* xl = (unsigned short*)w;            w += (long)NN * HID * 2;
  unsigned short* xr = (unsigned short*)w;            w += (long)NN * HID * 2;
  unsigned short* Wt = (unsigned short*)w;            w += 128 * 128 * 2;
  unsigned int* coarse = (unsigned int*)w;            w += (long)NBC * CCAP * 4;
  unsigned int* buckets = (unsigned int*)w;           w += (long)NBA * CAP * 4;
  unsigned short* sc16 = (unsigned short*)w;          w += (long)NBA * 32 * 2;
  int* gcnt = (int*)w;                                w += NBA * 4;
  int* gcurc = (int*)w;                               w += NBC * 4;
  float* pooled = (float*)w;                          w += NG * HID * 4;
  float* cnt = (float*)w;                             w += NG * 4;

  hipMemsetAsync(gcurc, 0, (size_t)(NBC + NG * HID + NG) * sizeof(int),
                 stream);

  k_prep<<<8, 256, 0, stream>>>(Wl, Wr, Wt);
  k_gemm<<<(NN + 127) / 128, 256, 0, stream>>>(x, Wt, xl, xr);
  k_coarse<<<(EE + 4095) / 4096, 256, 0, stream>>>(ei, gcurc, coarse);
  k_fine<<<NBC, 256, 0, stream>>>(gcurc, coarse, buckets, sc16, gcnt);
  k_pull2<<<NB, 256, 0, stream>>>(gcnt, buckets, sc16, xl, xr, att, bias,
                                  batch, pooled, cnt);
  k_final<<<1, NG * NOUT, 0, stream>>>(pooled, cnt, fc_w, fc_b, out);
}